// Round 1
// baseline (615.313 us; speedup 1.0000x reference)
//
#include <hip/hip_runtime.h>
#include <math.h>

// IDCT2 (DCT-III, ortho) over (16,32,256,256) fp32.
// Per 256x256 slice: Z = M * X * M^T, M[n][k] = w[k]*cos(pi*k*(2n+1)/(2N)).
// Pass 1: Y[b,i,n] = sum_k X[b,i,k] * M[n,k]
// Pass 2: Z[b,m,n] = sum_i M[m,i] * Y[b,i,n]
// M synthesized on the fly: phase q = k*(2n+1) mod 1024 (exact integer
// reduction, cos period = 2*pi <-> q period 1024), angle = q * pi/512.

constexpr int N = 256;
__device__ __forceinline__ float mval(int n, int k) {
    const float CST = 0.006135923151542565f;  // pi/512
    const float W0  = 0.0625f;                // 1/sqrt(256)
    const float WK  = 0.08838834764831845f;   // sqrt(2/256)
    float w = (k == 0) ? W0 : WK;
    int q = (k * (2 * n + 1)) & 1023;
    return w * __cosf(CST * (float)q);
}

// ---------------- Pass 1: Y = X * M^T (transform last axis) ----------------
// Block: 256 threads (16x16), 64x64 output tile, K-step 16.
// Ast[k][i] (A transposed in LDS) so each thread reads float4 (ds_read_b128).
__global__ __launch_bounds__(256) void idct_cols(const float* __restrict__ X,
                                                 float* __restrict__ Y) {
    const int n0 = blockIdx.x * 64;
    const int i0 = blockIdx.y * 64;
    const int b  = blockIdx.z;
    const float* Xb = X + (size_t)b * N * N;
    float* Yb = Y + (size_t)b * N * N;

    __shared__ float Ast[16][68];  // Ast[k][i] = X[b, i0+i, k0+k]
    __shared__ float Bs[16][68];   // Bs[k][n]  = M[n0+n, k0+k]

    const int tid = threadIdx.x;
    const int tx = tid & 15;   // n / 4
    const int ty = tid >> 4;   // i / 4

    float acc[4][4] = {};

    for (int k0 = 0; k0 < N; k0 += 16) {
        // Load A tile (64 rows x 16 k), transpose into LDS.
        {
            int r  = tid >> 2;          // 0..63 row
            int c4 = (tid & 3) << 2;    // 0,4,8,12
            float4 v = *reinterpret_cast<const float4*>(
                Xb + (size_t)(i0 + r) * N + k0 + c4);
            Ast[c4 + 0][r] = v.x; Ast[c4 + 1][r] = v.y;
            Ast[c4 + 2][r] = v.z; Ast[c4 + 3][r] = v.w;
        }
        // Synthesize B tile (16 k x 64 n).
        #pragma unroll
        for (int j = 0; j < 4; ++j) {
            int l  = tid + 256 * j;   // 0..1023
            int kk = l >> 6;
            int nn = l & 63;
            Bs[kk][nn] = mval(n0 + nn, k0 + kk);
        }
        __syncthreads();
        #pragma unroll
        for (int kk = 0; kk < 16; ++kk) {
            float4 av = *reinterpret_cast<const float4*>(&Ast[kk][ty << 2]);
            float4 bv = *reinterpret_cast<const float4*>(&Bs[kk][tx << 2]);
            float a[4] = {av.x, av.y, av.z, av.w};
            float bb[4] = {bv.x, bv.y, bv.z, bv.w};
            #pragma unroll
            for (int r = 0; r < 4; ++r)
                #pragma unroll
                for (int c = 0; c < 4; ++c)
                    acc[r][c] += a[r] * bb[c];
        }
        __syncthreads();
    }
    #pragma unroll
    for (int r = 0; r < 4; ++r) {
        float4 v = make_float4(acc[r][0], acc[r][1], acc[r][2], acc[r][3]);
        *reinterpret_cast<float4*>(
            Yb + (size_t)(i0 + (ty << 2) + r) * N + n0 + (tx << 2)) = v;
    }
}

// ---------------- Pass 2: Z = M * Y (transform row axis) ----------------
__global__ __launch_bounds__(256) void idct_rows(const float* __restrict__ Y,
                                                 float* __restrict__ Z) {
    const int n0 = blockIdx.x * 64;
    const int m0 = blockIdx.y * 64;
    const int b  = blockIdx.z;
    const float* Yb = Y + (size_t)b * N * N;
    float* Zb = Z + (size_t)b * N * N;

    __shared__ float Ast[16][68];  // Ast[i][m] = M[m0+m, k0+i]
    __shared__ float Bs[16][68];   // Bs[i][n]  = Y[b, k0+i, n0+n]

    const int tid = threadIdx.x;
    const int tx = tid & 15;   // n / 4
    const int ty = tid >> 4;   // m / 4

    float acc[4][4] = {};

    for (int k0 = 0; k0 < N; k0 += 16) {
        // Synthesize A tile (64 m x 16 i), stored transposed.
        #pragma unroll
        for (int j = 0; j < 4; ++j) {
            int l  = tid + 256 * j;   // 0..1023
            int ii = l >> 6;
            int mm = l & 63;
            Ast[ii][mm] = mval(m0 + mm, k0 + ii);
        }
        // Load B tile (16 i x 64 n) as float4.
        {
            int r  = tid >> 4;          // 0..15
            int c4 = (tid & 15) << 2;   // 0..60
            *reinterpret_cast<float4*>(&Bs[r][c4]) =
                *reinterpret_cast<const float4*>(
                    Yb + (size_t)(k0 + r) * N + n0 + c4);
        }
        __syncthreads();
        #pragma unroll
        for (int kk = 0; kk < 16; ++kk) {
            float4 av = *reinterpret_cast<const float4*>(&Ast[kk][ty << 2]);
            float4 bv = *reinterpret_cast<const float4*>(&Bs[kk][tx << 2]);
            float a[4] = {av.x, av.y, av.z, av.w};
            float bb[4] = {bv.x, bv.y, bv.z, bv.w};
            #pragma unroll
            for (int r = 0; r < 4; ++r)
                #pragma unroll
                for (int c = 0; c < 4; ++c)
                    acc[r][c] += a[r] * bb[c];
        }
        __syncthreads();
    }
    #pragma unroll
    for (int r = 0; r < 4; ++r) {
        float4 v = make_float4(acc[r][0], acc[r][1], acc[r][2], acc[r][3]);
        *reinterpret_cast<float4*>(
            Zb + (size_t)(m0 + (ty << 2) + r) * N + n0 + (tx << 2)) = v;
    }
}

// -------- Pass 2 fallback (ws too small): in-place on d_out per strip ------
// Each block owns a full 256-row x 64-col strip of one slice: stages it
// entirely in LDS, then overwrites it. No inter-block hazard.
__global__ __launch_bounds__(512) void idct_rows_inplace(float* __restrict__ Y) {
    const int n0 = blockIdx.x * 64;
    const int b  = blockIdx.y;
    float* Yb = Y + (size_t)b * N * N;

    __shared__ float Ys[256][68];   // full strip
    __shared__ float Ms[16][256];   // Ms[i][m] per K-step

    const int tid = threadIdx.x;

    #pragma unroll
    for (int j = 0; j < 8; ++j) {
        int l   = tid + 512 * j;     // 0..4095
        int row = l >> 4;
        int c4  = (l & 15) << 2;
        *reinterpret_cast<float4*>(&Ys[row][c4]) =
            *reinterpret_cast<const float4*>(Yb + (size_t)row * N + n0 + c4);
    }
    __syncthreads();

    const int tx = tid & 15;   // n / 4
    const int ty = tid >> 4;   // 0..31, m / 8
    float acc[8][4] = {};

    for (int i0 = 0; i0 < N; i0 += 16) {
        __syncthreads();  // protect Ms against previous iteration readers
        #pragma unroll
        for (int j = 0; j < 8; ++j) {
            int l  = tid + 512 * j;   // 0..4095
            int ii = l >> 8;
            int m  = l & 255;
            Ms[ii][m] = mval(m, i0 + ii);
        }
        __syncthreads();
        #pragma unroll
        for (int ii = 0; ii < 16; ++ii) {
            float bb[4];
            #pragma unroll
            for (int c = 0; c < 4; ++c) bb[c] = Ys[i0 + ii][(tx << 2) + c];
            #pragma unroll
            for (int r = 0; r < 8; ++r) {
                float a = Ms[ii][(ty << 3) + r];
                #pragma unroll
                for (int c = 0; c < 4; ++c) acc[r][c] += a * bb[c];
            }
        }
    }

    #pragma unroll
    for (int r = 0; r < 8; ++r) {
        float4 v = make_float4(acc[r][0], acc[r][1], acc[r][2], acc[r][3]);
        *reinterpret_cast<float4*>(
            Yb + (size_t)((ty << 3) + r) * N + n0 + (tx << 2)) = v;
    }
}

extern "C" void kernel_launch(void* const* d_in, const int* in_sizes, int n_in,
                              void* d_out, int out_size, void* d_ws, size_t ws_size,
                              hipStream_t stream) {
    const float* X = (const float*)d_in[0];
    float* out = (float*)d_out;
    const int total = in_sizes[0];          // 16*32*256*256
    const int Bn = total / (N * N);         // 512 slices
    const size_t interm_bytes = (size_t)total * sizeof(float);

    if (ws_size >= interm_bytes) {
        float* Ytmp = (float*)d_ws;
        idct_cols<<<dim3(N / 64, N / 64, Bn), 256, 0, stream>>>(X, Ytmp);
        idct_rows<<<dim3(N / 64, N / 64, Bn), 256, 0, stream>>>(Ytmp, out);
    } else {
        idct_cols<<<dim3(N / 64, N / 64, Bn), 256, 0, stream>>>(X, out);
        idct_rows_inplace<<<dim3(N / 64, Bn), 512, 0, stream>>>(out);
    }
}

// Round 3
// 327.877 us; speedup vs baseline: 1.8767x; 1.8767x over previous
//
#include <hip/hip_runtime.h>
#include <math.h>

// IDCT2 (DCT-III, ortho) over (16,32,256,256) fp32 via bf16 MFMA.
// Z = M * X * M^T, M[n][k] = w[k]*cos(pi*k*(2n+1)/512).
// mgen:   M bf16 -> ws (128 KB)
// gemm_p1: Yt[n][i] = sum_k X[i,k] M[n,k]   (transposed intermediate, bf16)
// gemm_p2: Z[m][n]  = sum_i Yt[n,i] M[m,i]  (transpose epilogue, fp32)

constexpr int N = 256;
typedef __attribute__((ext_vector_type(8))) short short8;
typedef __attribute__((ext_vector_type(4))) float f32x4;

__device__ __forceinline__ unsigned short f2bf(float f) {
    unsigned int u = __float_as_uint(f);
    u += 0x7fffu + ((u >> 16) & 1u);
    return (unsigned short)(u >> 16);
}

__device__ __forceinline__ float mvalf(int n, int k) {
    const float CST = 0.006135923151542565f;  // pi/512
    const float W0  = 0.0625f;                // 1/sqrt(256)
    const float WK  = 0.08838834764831845f;   // sqrt(2/256)
    int q = (k * (2 * n + 1)) & 1023;
    return ((k == 0) ? W0 : WK) * __cosf(CST * (float)q);
}

__global__ __launch_bounds__(256) void mgen(unsigned short* __restrict__ Mg) {
    int idx = blockIdx.x * 256 + threadIdx.x;
    int n = idx >> 8, k = idx & 255;
    Mg[idx] = f2bf(mvalf(n, k));
}

// ---------------- Pass 1: Yt = (X * M^T)^T, bf16 out ----------------
__global__ __launch_bounds__(256) void gemm_p1(const float* __restrict__ X,
                                               const unsigned short* __restrict__ Mg,
                                               unsigned short* __restrict__ Yt) {
    const int n0 = blockIdx.x * 128;
    const int i0 = blockIdx.y * 128;
    const float* Xb = X + (size_t)blockIdx.z * N * N;
    unsigned short* Ytb = Yt + (size_t)blockIdx.z * N * N;

    __shared__ union {
        struct { unsigned short A[128][40]; unsigned short B[128][40]; } s;
        unsigned short T[128][72];
    } sm;

    const int tid = threadIdx.x;
    const int w = tid >> 6, l = tid & 63;
    const int q = l >> 4, lr = l & 15;
    const int wr = w >> 1, wc = w & 1;
    const int sr = tid >> 1, sh = tid & 1;

    f32x4 acc[4][4];
    #pragma unroll
    for (int r = 0; r < 4; ++r)
        #pragma unroll
        for (int c = 0; c < 4; ++c) acc[r][c] = f32x4{0.f, 0.f, 0.f, 0.f};

    for (int k0 = 0; k0 < N; k0 += 32) {
        {   // A tile: X rows (fp32 -> bf16), k-contiguous
            const float* src = Xb + (size_t)(i0 + sr) * N + k0 + sh * 16;
            float4 v0 = ((const float4*)src)[0];
            float4 v1 = ((const float4*)src)[1];
            float4 v2 = ((const float4*)src)[2];
            float4 v3 = ((const float4*)src)[3];
            ushort4 p0 = {f2bf(v0.x), f2bf(v0.y), f2bf(v0.z), f2bf(v0.w)};
            ushort4 p1 = {f2bf(v1.x), f2bf(v1.y), f2bf(v1.z), f2bf(v1.w)};
            ushort4 p2 = {f2bf(v2.x), f2bf(v2.y), f2bf(v2.z), f2bf(v2.w)};
            ushort4 p3 = {f2bf(v3.x), f2bf(v3.y), f2bf(v3.z), f2bf(v3.w)};
            *(ushort4*)&sm.s.A[sr][sh * 16 + 0]  = p0;
            *(ushort4*)&sm.s.A[sr][sh * 16 + 4]  = p1;
            *(ushort4*)&sm.s.A[sr][sh * 16 + 8]  = p2;
            *(ushort4*)&sm.s.A[sr][sh * 16 + 12] = p3;
        }
        {   // B tile: M rows, bf16, k-contiguous
            const unsigned short* src = Mg + (n0 + sr) * N + k0 + sh * 16;
            uint4 m0 = ((const uint4*)src)[0];
            uint4 m1 = ((const uint4*)src)[1];
            *(uint4*)&sm.s.B[sr][sh * 16 + 0] = m0;
            *(uint4*)&sm.s.B[sr][sh * 16 + 8] = m1;
        }
        __syncthreads();
        short8 afr[4], bfr[4];
        #pragma unroll
        for (int r = 0; r < 4; ++r)
            afr[r] = *(const short8*)&sm.s.A[wr * 64 + r * 16 + lr][q * 8];
        #pragma unroll
        for (int c = 0; c < 4; ++c)
            bfr[c] = *(const short8*)&sm.s.B[wc * 64 + c * 16 + lr][q * 8];
        #pragma unroll
        for (int r = 0; r < 4; ++r)
            #pragma unroll
            for (int c = 0; c < 4; ++c)
                acc[r][c] = __builtin_amdgcn_mfma_f32_16x16x32_bf16(
                    afr[r], bfr[c], acc[r][c], 0, 0, 0);
        __syncthreads();
    }

    // Epilogue: transpose through LDS, write Yt[n][i] bf16 coalesced.
    // acc[r][c][reg] = Y[i = i0 + wr*64 + r*16 + q*4 + reg]
    //                   [n = n0 + wc*64 + c*16 + lr]
    #pragma unroll
    for (int ch = 0; ch < 2; ++ch) {
        if (wr == ch) {
            #pragma unroll
            for (int r = 0; r < 4; ++r)
                #pragma unroll
                for (int c = 0; c < 4; ++c) {
                    ushort4 p = {f2bf(acc[r][c][0]), f2bf(acc[r][c][1]),
                                 f2bf(acc[r][c][2]), f2bf(acc[r][c][3])};
                    *(ushort4*)&sm.T[wc * 64 + c * 16 + lr][r * 16 + q * 4] = p;
                }
        }
        __syncthreads();
        {
            int row = tid >> 1, hh = tid & 1;
            unsigned short* dst = Ytb + (size_t)(n0 + row) * N + i0 + ch * 64 + hh * 32;
            const uint4* s4 = (const uint4*)&sm.T[row][hh * 32];
            uint4 a0 = s4[0], a1 = s4[1], a2 = s4[2], a3 = s4[3];
            ((uint4*)dst)[0] = a0; ((uint4*)dst)[1] = a1;
            ((uint4*)dst)[2] = a2; ((uint4*)dst)[3] = a3;
        }
        __syncthreads();
    }
}

// ---------------- Pass 2: Z[m][n] = sum_i Yt[n][i] M[m][i], fp32 out ------
__global__ __launch_bounds__(256) void gemm_p2(const unsigned short* __restrict__ Yt,
                                               const unsigned short* __restrict__ Mg,
                                               float* __restrict__ Z) {
    const int m0 = blockIdx.x * 128;
    const int n0 = blockIdx.y * 128;
    const unsigned short* Ytb = Yt + (size_t)blockIdx.z * N * N;
    float* Zb = Z + (size_t)blockIdx.z * N * N;

    __shared__ union {
        struct { unsigned short A[128][40]; unsigned short B[128][40]; } s;
        float T[32][132];
    } sm;

    const int tid = threadIdx.x;
    const int w = tid >> 6, l = tid & 63;
    const int q = l >> 4, lr = l & 15;
    const int wr = w >> 1, wc = w & 1;
    const int sr = tid >> 1, sh = tid & 1;

    f32x4 acc[4][4];
    #pragma unroll
    for (int r = 0; r < 4; ++r)
        #pragma unroll
        for (int c = 0; c < 4; ++c) acc[r][c] = f32x4{0.f, 0.f, 0.f, 0.f};

    for (int k0 = 0; k0 < N; k0 += 32) {
        {   // A tile: Yt rows (n), bf16
            const unsigned short* src = Ytb + (size_t)(n0 + sr) * N + k0 + sh * 16;
            uint4 a0 = ((const uint4*)src)[0];
            uint4 a1 = ((const uint4*)src)[1];
            *(uint4*)&sm.s.A[sr][sh * 16 + 0] = a0;
            *(uint4*)&sm.s.A[sr][sh * 16 + 8] = a1;
        }
        {   // B tile: M rows (m), bf16
            const unsigned short* src = Mg + (m0 + sr) * N + k0 + sh * 16;
            uint4 m0v = ((const uint4*)src)[0];
            uint4 m1v = ((const uint4*)src)[1];
            *(uint4*)&sm.s.B[sr][sh * 16 + 0] = m0v;
            *(uint4*)&sm.s.B[sr][sh * 16 + 8] = m1v;
        }
        __syncthreads();
        short8 afr[4], bfr[4];
        #pragma unroll
        for (int r = 0; r < 4; ++r)
            afr[r] = *(const short8*)&sm.s.A[wr * 64 + r * 16 + lr][q * 8];
        #pragma unroll
        for (int c = 0; c < 4; ++c)
            bfr[c] = *(const short8*)&sm.s.B[wc * 64 + c * 16 + lr][q * 8];
        #pragma unroll
        for (int r = 0; r < 4; ++r)
            #pragma unroll
            for (int c = 0; c < 4; ++c)
                acc[r][c] = __builtin_amdgcn_mfma_f32_16x16x32_bf16(
                    afr[r], bfr[c], acc[r][c], 0, 0, 0);
        __syncthreads();
    }

    // Epilogue: acc[r][c][reg] = V[n_loc][m_loc] = Z[m][n] with
    //   n_loc = wr*64 + r*16 + q*4 + reg, m_loc = wc*64 + c*16 + lr.
    // Transpose 32 m-rows at a time. FIX vs round 2: column index must
    // include wr*64 (both wr waves participate; they cover disjoint n).
    #pragma unroll
    for (int ch = 0; ch < 4; ++ch) {
        if (wc == (ch >> 1)) {
            #pragma unroll
            for (int cc = 0; cc < 2; ++cc) {
                int c = (ch & 1) * 2 + cc;
                int mp = cc * 16 + lr;   // m_loc - ch*32
                #pragma unroll
                for (int r = 0; r < 4; ++r) {
                    float4 p = {acc[r][c][0], acc[r][c][1], acc[r][c][2], acc[r][c][3]};
                    *(float4*)&sm.T[mp][wr * 64 + r * 16 + q * 4] = p;
                }
            }
        }
        __syncthreads();
        {
            int row = tid >> 3, seg = tid & 7;
            float* dst = Zb + (size_t)(m0 + ch * 32 + row) * N + n0 + seg * 16;
            const float4* s4 = (const float4*)&sm.T[row][seg * 16];
            float4 a0 = s4[0], a1 = s4[1], a2 = s4[2], a3 = s4[3];
            ((float4*)dst)[0] = a0; ((float4*)dst)[1] = a1;
            ((float4*)dst)[2] = a2; ((float4*)dst)[3] = a3;
        }
        __syncthreads();
    }
}

// ================= fp32 fallback (ws too small) — round-1 kernels =========
__global__ __launch_bounds__(256) void idct_cols(const float* __restrict__ X,
                                                 float* __restrict__ Y) {
    const int n0 = blockIdx.x * 64;
    const int i0 = blockIdx.y * 64;
    const float* Xb = X + (size_t)blockIdx.z * N * N;
    float* Yb = Y + (size_t)blockIdx.z * N * N;
    __shared__ float Ast[16][68];
    __shared__ float Bs[16][68];
    const int tid = threadIdx.x;
    const int tx = tid & 15, ty = tid >> 4;
    float acc[4][4] = {};
    for (int k0 = 0; k0 < N; k0 += 16) {
        {
            int r = tid >> 2, c4 = (tid & 3) << 2;
            float4 v = *reinterpret_cast<const float4*>(Xb + (size_t)(i0 + r) * N + k0 + c4);
            Ast[c4 + 0][r] = v.x; Ast[c4 + 1][r] = v.y;
            Ast[c4 + 2][r] = v.z; Ast[c4 + 3][r] = v.w;
        }
        #pragma unroll
        for (int j = 0; j < 4; ++j) {
            int ll = tid + 256 * j;
            Bs[ll >> 6][ll & 63] = mvalf(n0 + (ll & 63), k0 + (ll >> 6));
        }
        __syncthreads();
        #pragma unroll
        for (int kk = 0; kk < 16; ++kk) {
            float4 av = *reinterpret_cast<const float4*>(&Ast[kk][ty << 2]);
            float4 bv = *reinterpret_cast<const float4*>(&Bs[kk][tx << 2]);
            float a[4] = {av.x, av.y, av.z, av.w};
            float bb[4] = {bv.x, bv.y, bv.z, bv.w};
            #pragma unroll
            for (int r = 0; r < 4; ++r)
                #pragma unroll
                for (int c = 0; c < 4; ++c) acc[r][c] += a[r] * bb[c];
        }
        __syncthreads();
    }
    #pragma unroll
    for (int r = 0; r < 4; ++r) {
        float4 v = make_float4(acc[r][0], acc[r][1], acc[r][2], acc[r][3]);
        *reinterpret_cast<float4*>(Yb + (size_t)(i0 + (ty << 2) + r) * N + n0 + (tx << 2)) = v;
    }
}

__global__ __launch_bounds__(512) void idct_rows_inplace(float* __restrict__ Y) {
    const int n0 = blockIdx.x * 64;
    float* Yb = Y + (size_t)blockIdx.y * N * N;
    __shared__ float Ys[256][68];
    __shared__ float Ms[16][256];
    const int tid = threadIdx.x;
    #pragma unroll
    for (int j = 0; j < 8; ++j) {
        int ll = tid + 512 * j;
        int row = ll >> 4, c4 = (ll & 15) << 2;
        *reinterpret_cast<float4*>(&Ys[row][c4]) =
            *reinterpret_cast<const float4*>(Yb + (size_t)row * N + n0 + c4);
    }
    __syncthreads();
    const int tx = tid & 15, ty = tid >> 4;
    float acc[8][4] = {};
    for (int i0 = 0; i0 < N; i0 += 16) {
        __syncthreads();
        #pragma unroll
        for (int j = 0; j < 8; ++j) {
            int ll = tid + 512 * j;
            Ms[ll >> 8][ll & 255] = mvalf(ll & 255, i0 + (ll >> 8));
        }
        __syncthreads();
        #pragma unroll
        for (int ii = 0; ii < 16; ++ii) {
            float bb[4];
            #pragma unroll
            for (int c = 0; c < 4; ++c) bb[c] = Ys[i0 + ii][(tx << 2) + c];
            #pragma unroll
            for (int r = 0; r < 8; ++r) {
                float a = Ms[ii][(ty << 3) + r];
                #pragma unroll
                for (int c = 0; c < 4; ++c) acc[r][c] += a * bb[c];
            }
        }
    }
    #pragma unroll
    for (int r = 0; r < 8; ++r) {
        float4 v = make_float4(acc[r][0], acc[r][1], acc[r][2], acc[r][3]);
        *reinterpret_cast<float4*>(Yb + (size_t)((ty << 3) + r) * N + n0 + (tx << 2)) = v;
    }
}

extern "C" void kernel_launch(void* const* d_in, const int* in_sizes, int n_in,
                              void* d_out, int out_size, void* d_ws, size_t ws_size,
                              hipStream_t stream) {
    const float* X = (const float*)d_in[0];
    float* out = (float*)d_out;
    const int total = in_sizes[0];
    const int Bn = total / (N * N);   // 512
    const size_t need = (size_t)N * N * 2 + (size_t)total * 2;  // M + Yt bf16

    if (ws_size >= need) {
        unsigned short* Mg = (unsigned short*)d_ws;
        unsigned short* Yt = Mg + N * N;
        mgen<<<N * N / 256, 256, 0, stream>>>(Mg);
        gemm_p1<<<dim3(2, 2, Bn), 256, 0, stream>>>(X, Mg, Yt);
        gemm_p2<<<dim3(2, 2, Bn), 256, 0, stream>>>(Yt, Mg, out);
    } else {
        idct_cols<<<dim3(N / 64, N / 64, Bn), 256, 0, stream>>>(X, out);
        idct_rows_inplace<<<dim3(N / 64, Bn), 512, 0, stream>>>(out);
    }
}